// Round 8
// baseline (167.540 us; speedup 1.0000x reference)
//
#include <hip/hip_runtime.h>

#define BB 4
#define CCH 256
#define OCH 256
#define HH 64
#define WW 64
#define HWSZ 4096

typedef __bf16 bf16_t;
typedef bf16_t bf16x8 __attribute__((ext_vector_type(8)));
typedef float f32x4 __attribute__((ext_vector_type(4)));

__device__ __forceinline__ unsigned int bpack(float a, float b) {
    unsigned int ua = __float_as_uint(a);
    ua = (ua + 0x7FFFu + ((ua >> 16) & 1u)) >> 16;
    unsigned int ub = __float_as_uint(b);
    ub = (ub + 0x7FFFu + ((ub >> 16) & 1u)) >> 16;
    return ua | (ub << 16);
}
__device__ __forceinline__ float blo(unsigned int u) { return __uint_as_float(u << 16); }
__device__ __forceinline__ float bhi(unsigned int u) { return __uint_as_float(u & 0xFFFF0000u); }

// ---------------------------------------------------------------------------
// Kernel 0: transpose x [B][C][H][W] f32 -> xT [B][H][W][C] bf16
// ---------------------------------------------------------------------------
__global__ __launch_bounds__(256) void k_xT(const float* __restrict__ x,
                                            ushort* __restrict__ xT) {
    int b = blockIdx.x >> 6;
    int h = blockIdx.x & 63;
    int tid = threadIdx.x;
    int wv = tid >> 6;
    int lane = tid & 63;

    __shared__ unsigned int buf[64][130];

    const float* xp = x + ((size_t)b * CCH + wv * 64) * HWSZ + h * WW + lane;
#pragma unroll 8
    for (int i = 0; i < 32; ++i) {
        float a = xp[(size_t)(2 * i) * HWSZ];
        float c = xp[(size_t)(2 * i + 1) * HWSZ];
        buf[lane][wv * 32 + i] = bpack(a, c);
    }
    __syncthreads();

    ushort* dst = xT + ((size_t)(b * 64 + h) * 64) * 256;
#pragma unroll
    for (int r = 0; r < 16; ++r) {
        int idx = tid + r * 256;
        int w = idx >> 6;
        int q = idx & 63;
        uint2 v = *(const uint2*)&buf[w][2 * q];
        *(uint2*)(dst + (size_t)w * 256 + q * 4) = v;
    }
}

// ---------------------------------------------------------------------------
// Kernel prep (merged): w1F repack | w2F repack | P zero | out bias-prefill
// ---------------------------------------------------------------------------
__global__ void k_prep(const float* __restrict__ w_off, const float* __restrict__ w_def,
                       const float* __restrict__ b_def,
                       ushort* __restrict__ w1F, ushort* __restrict__ w2F,
                       float* __restrict__ P, float* __restrict__ out) {
    int i = blockIdx.x * blockDim.x + threadIdx.x;
    if (i < 73728) {
        int j = i & 7;
        int o = (i >> 3) & 31;
        int cSub = (i >> 8) & 31;
        int k = i >> 13;
        float v = 0.0f;
        if (o < 27) v = w_off[((size_t)o * CCH + cSub * 8 + j) * 9 + k];
        unsigned int u = __float_as_uint(v);
        u = (u + 0x7FFFu + ((u >> 16) & 1u)) >> 16;
        w1F[i] = (ushort)u;
        return;
    }
    i -= 73728;
    if (i < 589824) {
        int j = i & 7;
        int o = (i >> 3) & 255;
        int cg = (i >> 11) & 31;
        int k = i >> 16;
        float v = w_def[(size_t)o * 2304 + (cg * 8 + j) * 9 + k];
        unsigned int u = __float_as_uint(v);
        u = (u + 0x7FFFu + ((u >> 16) & 1u)) >> 16;
        w2F[i] = (ushort)u;
        return;
    }
    i -= 589824;
    if (i < 110592) {
        ((float4*)P)[i] = make_float4(0.f, 0.f, 0.f, 0.f);
        return;
    }
    i -= 110592;
    if (i < 1048576) {
        float v = b_def[(i >> 10) & 255];
        ((float4*)out)[i] = make_float4(v, v, v, v);
    }
}

// ---------------------------------------------------------------------------
// Kernel 2: pred conv via MFMA, B staged densely from xT. Atomic K-split x4.
// grid = 1024, XCD-swizzled.
// ---------------------------------------------------------------------------
__global__ __launch_bounds__(256) void k_pred3(const ushort* __restrict__ xT,
                                               const ushort* __restrict__ w1F,
                                               float* __restrict__ P) {
    int bid = blockIdx.x;
    int L = (bid & 7) * 128 + (bid >> 3);
    int g = L & 3;
    int h = (L >> 2) & 63;
    int b = L >> 8;
    int tid = threadIdx.x;
    int spx  = tid & 63;
    int sgrp = tid >> 6;
    int lane = tid & 63;
    int wv   = tid >> 6;
    int l16  = lane & 15;
    int lq   = lane >> 4;

    __shared__ ushort b_lds[2][4][4][16][8];

    const ushort* xTb = xT + (size_t)b * HWSZ * 256;
    const bf16x8* w1v = (const bf16x8*)w1F;

    f32x4 acc[2];
    acc[0] = (f32x4){0.f, 0.f, 0.f, 0.f};
    acc[1] = (f32x4){0.f, 0.f, 0.f, 0.f};

    auto stage = [&](int t, int buf) {
        int cg = 2 * g + (t >= 9);
        int k = t - (t >= 9 ? 9 : 0);
        int y   = h + k / 3 - 1;
        int pxs = spx + k % 3 - 1;
        bool ok = (y >= 0 && y < HH && pxs >= 0 && pxs < WW);
        uint4 v = make_uint4(0u, 0u, 0u, 0u);
        if (ok) v = *(const uint4*)(xTb + (size_t)(y * WW + pxs) * 256 + cg * 32 + sgrp * 8);
        *(uint4*)&b_lds[buf][sgrp][spx >> 4][spx & 15][0] = v;
    };

    stage(0, 0);
    __syncthreads();

    for (int t = 0; t < 18; ++t) {
        int cur = t & 1;
        int cg = 2 * g + (t >= 9);
        int k  = t - (t >= 9 ? 9 : 0);
        int row = k * 32 + cg * 4 + lq;
        bf16x8 a0 = w1v[(size_t)row * 32 + 0 * 16 + l16];
        bf16x8 a1 = w1v[(size_t)row * 32 + 1 * 16 + l16];
        if (t < 17) stage(t + 1, cur ^ 1);
        bf16x8 bfrag = *(const bf16x8*)&b_lds[cur][lq][wv][l16][0];
        acc[0] = __builtin_amdgcn_mfma_f32_16x16x32_bf16(a0, bfrag, acc[0], 0, 0, 0);
        acc[1] = __builtin_amdgcn_mfma_f32_16x16x32_bf16(a1, bfrag, acc[1], 0, 0, 0);
        __syncthreads();
    }

#pragma unroll
    for (int mf = 0; mf < 2; ++mf) {
#pragma unroll
        for (int r = 0; r < 4; ++r) {
            int o = mf * 16 + lq * 4 + r;
            if (o < 27) {
                atomicAdd(&P[((size_t)b * 27 + o) * HWSZ + h * WW + wv * 16 + l16],
                          acc[mf][r]);
            }
        }
    }
}

// ---------------------------------------------------------------------------
// Kernel 3: deformable sampling + bf16 MFMA GEMM, deep-pipelined.
// Tile 256o x 64px, 512 thr, cs-split x2, grid 512, XCD-swizzled.
// B-gathers 2 chunks ahead (reg slots + wgt snapshot), A-frags 1 chunk ahead
// (ping-pong), P/bias reads 1 chunk ahead of desc calc. All vmcnt waits hit
// data >= 1 barrier-period old.
// ---------------------------------------------------------------------------
__global__ __launch_bounds__(512, 4) void k_deform7(const ushort* __restrict__ xT,
                                                    const float* __restrict__ P,
                                                    const float* __restrict__ b_off,
                                                    const ushort* __restrict__ w2F,
                                                    float* __restrict__ out) {
    int bid = blockIdx.x;
    int L = (bid & 7) * 64 + (bid >> 3);
    int cs = L & 1;
    int h  = (L >> 1) & 63;
    int b  = L >> 7;
    int tid = threadIdx.x;
    int lane = tid & 63;
    int wv   = tid >> 6;
    int l16  = lane & 15;
    int lq   = lane >> 4;
    int px   = tid >> 3;
    int cl   = tid & 7;

    __shared__ ushort b_lds[2][8][4][16][8];   // 16KB

    const char* xTc = (const char*)xT + (size_t)b * HWSZ * 512 + cs * 256 + cl * 16;
    const bf16x8* w2b = (const bf16x8*)w2F + (size_t)(cs * 16) * 256 + wv * 32 + l16;

    uint4* wdst[2];
    wdst[0] = (uint4*)&b_lds[0][cl][px >> 4][(px & 15) ^ cl][0];
    wdst[1] = (uint4*)&b_lds[1][cl][px >> 4][(px & 15) ^ cl][0];

    f32x4 acc[2][4];
#pragma unroll
    for (int mf = 0; mf < 2; ++mf)
#pragma unroll
        for (int nt = 0; nt < 4; ++nt) acc[mf][nt] = (f32x4){0.f, 0.f, 0.f, 0.f};

    const float* Pb = P + (size_t)b * 27 * HWSZ + h * WW + px;

    float pOy, pOx, pMr, bOy, bOx, bMr;
    float wgt[4];
    const char* aptr[4];

    auto loadP = [&](int k) {
        pOy = Pb[(size_t)(2 * k) * HWSZ];
        pOx = Pb[(size_t)(2 * k + 1) * HWSZ];
        pMr = Pb[(size_t)(18 + k) * HWSZ];
        bOy = b_off[2 * k];
        bOx = b_off[2 * k + 1];
        bMr = b_off[18 + k];
    };
    auto calcDesc = [&](int k) {
        float offy = pOy + bOy;
        float offx = pOx + bOx;
        float m = 1.0f / (1.0f + expf(-(pMr + bMr)));
        float sy = offy + (float)(h + k / 3 - 1);
        float sx = offx + (float)(px + k % 3 - 1);
        float y0f = floorf(sy), x0f = floorf(sx);
        float ty = sy - y0f, tx = sx - x0f;
        int y0 = (int)y0f, x0 = (int)x0f;
#pragma unroll
        for (int dy = 0; dy < 2; ++dy) {
#pragma unroll
            for (int dx = 0; dx < 2; ++dx) {
                int yi = y0 + dy, xi = x0 + dx;
                bool ok = (yi >= 0 && yi < HH && xi >= 0 && xi < WW);
                float wg = (dy ? ty : 1.0f - ty) * (dx ? tx : 1.0f - tx) * m;
                wgt[dy * 2 + dx]  = ok ? wg : 0.0f;
                aptr[dy * 2 + dx] = xTc + (size_t)(ok ? (yi * WW + xi) : 0) * 512;
            }
        }
    };

    uint4 gbS[2][4];
    float wgtS[2][4];
    auto issueGather = [&](int u) {
        int s = u & 1;
        int off = s * 128;
#pragma unroll
        for (int c = 0; c < 4; ++c) gbS[s][c] = *(const uint4*)(aptr[c] + off);
#pragma unroll
        for (int c = 0; c < 4; ++c) wgtS[s][c] = wgt[c];
    };
    auto combineS = [&](int s) -> uint4 {
        uint4 r;
        float w0 = wgtS[s][0], w1 = wgtS[s][1], w2 = wgtS[s][2], w3 = wgtS[s][3];
        uint4 g0 = gbS[s][0], g1 = gbS[s][1], g2 = gbS[s][2], g3 = gbS[s][3];
        {
            float lo = w0*blo(g0.x) + w1*blo(g1.x) + w2*blo(g2.x) + w3*blo(g3.x);
            float hi = w0*bhi(g0.x) + w1*bhi(g1.x) + w2*bhi(g2.x) + w3*bhi(g3.x);
            r.x = bpack(lo, hi);
        }
        {
            float lo = w0*blo(g0.y) + w1*blo(g1.y) + w2*blo(g2.y) + w3*blo(g3.y);
            float hi = w0*bhi(g0.y) + w1*bhi(g1.y) + w2*bhi(g2.y) + w3*bhi(g3.y);
            r.y = bpack(lo, hi);
        }
        {
            float lo = w0*blo(g0.z) + w1*blo(g1.z) + w2*blo(g2.z) + w3*blo(g3.z);
            float hi = w0*bhi(g0.z) + w1*bhi(g1.z) + w2*bhi(g2.z) + w3*bhi(g3.z);
            r.z = bpack(lo, hi);
        }
        {
            float lo = w0*blo(g0.w) + w1*blo(g1.w) + w2*blo(g2.w) + w3*blo(g3.w);
            float hi = w0*bhi(g0.w) + w1*bhi(g1.w) + w2*bhi(g2.w) + w3*bhi(g3.w);
            r.w = bpack(lo, hi);
        }
        return r;
    };

    bf16x8 aS[2][2][2];
    auto loadA = [&](int t) {
        int s = t & 1;
        size_t base = ((size_t)((t >> 1) * 32 + (t & 1) * 8) + lq) * 256;
#pragma unroll
        for (int g = 0; g < 2; ++g)
#pragma unroll
            for (int mf = 0; mf < 2; ++mf)
                aS[s][mf][g] = w2b[base + (size_t)g * 1024 + mf * 16];
    };

    // prologue
    loadP(0);
    calcDesc(0);
    issueGather(0);
    issueGather(1);
    loadP(1);
    loadA(0);
    *wdst[0] = combineS(0);
    __syncthreads();

#pragma unroll 2
    for (int t = 0; t < 18; ++t) {
        int cur = t & 1;
        if (t + 2 < 18) {
            if ((t & 1) == 0) calcDesc((t + 2) >> 1);
            issueGather(t + 2);
        }
        if (((t & 1) == 1) && (t + 3 < 18)) loadP((t + 3) >> 1);
        if (t + 1 < 18) loadA(t + 1);

        bf16x8 bfr[2][4];
#pragma unroll
        for (int g = 0; g < 2; ++g) {
            int kg = g * 4 + lq;
#pragma unroll
            for (int nt = 0; nt < 4; ++nt)
                bfr[g][nt] = *(const bf16x8*)&b_lds[cur][kg][nt][l16 ^ kg][0];
        }
#pragma unroll
        for (int g = 0; g < 2; ++g)
#pragma unroll
            for (int mf = 0; mf < 2; ++mf)
#pragma unroll
                for (int nt = 0; nt < 4; ++nt)
                    acc[mf][nt] = __builtin_amdgcn_mfma_f32_16x16x32_bf16(aS[cur][mf][g], bfr[g][nt], acc[mf][nt], 0, 0, 0);

        if (t + 1 < 18) *wdst[cur ^ 1] = combineS(cur ^ 1);
        __syncthreads();
    }

    // epilogue: atomic accumulate (out prefilled with bias)
#pragma unroll
    for (int mf = 0; mf < 2; ++mf) {
#pragma unroll
        for (int nt = 0; nt < 4; ++nt) {
#pragma unroll
            for (int r = 0; r < 4; ++r) {
                int o = wv * 32 + mf * 16 + lq * 4 + r;
                atomicAdd(&out[((size_t)b * OCH + o) * HWSZ + h * WW + nt * 16 + l16],
                          acc[mf][nt][r]);
            }
        }
    }
}

// ---------------------------------------------------------------------------
extern "C" void kernel_launch(void* const* d_in, const int* in_sizes, int n_in,
                              void* d_out, int out_size, void* d_ws, size_t ws_size,
                              hipStream_t stream) {
    const float* x     = (const float*)d_in[0];
    const float* w_off = (const float*)d_in[1];
    const float* b_off = (const float*)d_in[2];
    const float* w_def = (const float*)d_in[3];
    const float* b_def = (const float*)d_in[4];
    float* out = (float*)d_out;

    float*  P   = (float*)d_ws;                            // 442368 f32
    ushort* w1F = (ushort*)(P + (size_t)BB * 27 * HWSZ);   // 73728 bf16
    ushort* w2F = w1F + 73728;                             // 589824 bf16
    ushort* xT  = w2F + 589824;                            // 4.19M bf16

    hipLaunchKernelGGL(k_prep, dim3(7120), dim3(256), 0, stream,
                       w_off, w_def, b_def, w1F, w2F, P, out);
    hipLaunchKernelGGL(k_xT, dim3(BB * HH), dim3(256), 0, stream, x, xT);
    hipLaunchKernelGGL(k_pred3, dim3(1024), dim3(256), 0, stream, xT, w1F, P);
    hipLaunchKernelGGL(k_deform7, dim3(512), dim3(512), 0, stream, xT, P, b_off, w2F, out);
}

// Round 9
// 89.902 us; speedup vs baseline: 1.8636x; 1.8636x over previous
//
#include <hip/hip_runtime.h>

#define BB 4
#define CCH 256
#define OCH 256
#define HH 64
#define WW 64
#define HWSZ 4096

typedef __bf16 bf16_t;
typedef bf16_t bf16x8 __attribute__((ext_vector_type(8)));
typedef float f32x4 __attribute__((ext_vector_type(4)));

__device__ __forceinline__ unsigned int bpack(float a, float b) {
    unsigned int ua = __float_as_uint(a);
    ua = (ua + 0x7FFFu + ((ua >> 16) & 1u)) >> 16;
    unsigned int ub = __float_as_uint(b);
    ub = (ub + 0x7FFFu + ((ub >> 16) & 1u)) >> 16;
    return ua | (ub << 16);
}
__device__ __forceinline__ float blo(unsigned int u) { return __uint_as_float(u << 16); }
__device__ __forceinline__ float bhi(unsigned int u) { return __uint_as_float(u & 0xFFFF0000u); }

// ---------------------------------------------------------------------------
// Kernel 0: transpose x [B][C][H][W] f32 -> xT [B][H][W][C] bf16
// ---------------------------------------------------------------------------
__global__ __launch_bounds__(256) void k_xT(const float* __restrict__ x,
                                            ushort* __restrict__ xT) {
    int b = blockIdx.x >> 6;
    int h = blockIdx.x & 63;
    int tid = threadIdx.x;
    int wv = tid >> 6;
    int lane = tid & 63;

    __shared__ unsigned int buf[64][130];

    const float* xp = x + ((size_t)b * CCH + wv * 64) * HWSZ + h * WW + lane;
#pragma unroll 8
    for (int i = 0; i < 32; ++i) {
        float a = xp[(size_t)(2 * i) * HWSZ];
        float c = xp[(size_t)(2 * i + 1) * HWSZ];
        buf[lane][wv * 32 + i] = bpack(a, c);
    }
    __syncthreads();

    ushort* dst = xT + ((size_t)(b * 64 + h) * 64) * 256;
#pragma unroll
    for (int r = 0; r < 16; ++r) {
        int idx = tid + r * 256;
        int w = idx >> 6;
        int q = idx & 63;
        uint2 v = *(const uint2*)&buf[w][2 * q];
        *(uint2*)(dst + (size_t)w * 256 + q * 4) = v;
    }
}

// ---------------------------------------------------------------------------
// Kernel prep (merged): w1F repack | w2F repack | P zero | out bias-prefill
// ---------------------------------------------------------------------------
__global__ void k_prep(const float* __restrict__ w_off, const float* __restrict__ w_def,
                       const float* __restrict__ b_def,
                       ushort* __restrict__ w1F, ushort* __restrict__ w2F,
                       float* __restrict__ P, float* __restrict__ out) {
    int i = blockIdx.x * blockDim.x + threadIdx.x;
    if (i < 73728) {
        int j = i & 7;
        int o = (i >> 3) & 31;
        int cSub = (i >> 8) & 31;
        int k = i >> 13;
        float v = 0.0f;
        if (o < 27) v = w_off[((size_t)o * CCH + cSub * 8 + j) * 9 + k];
        unsigned int u = __float_as_uint(v);
        u = (u + 0x7FFFu + ((u >> 16) & 1u)) >> 16;
        w1F[i] = (ushort)u;
        return;
    }
    i -= 73728;
    if (i < 589824) {
        int j = i & 7;
        int o = (i >> 3) & 255;
        int cg = (i >> 11) & 31;
        int k = i >> 16;
        float v = w_def[(size_t)o * 2304 + (cg * 8 + j) * 9 + k];
        unsigned int u = __float_as_uint(v);
        u = (u + 0x7FFFu + ((u >> 16) & 1u)) >> 16;
        w2F[i] = (ushort)u;
        return;
    }
    i -= 589824;
    if (i < 110592) {
        ((float4*)P)[i] = make_float4(0.f, 0.f, 0.f, 0.f);
        return;
    }
    i -= 110592;
    if (i < 1048576) {
        float v = b_def[(i >> 10) & 255];
        ((float4*)out)[i] = make_float4(v, v, v, v);
    }
}

// ---------------------------------------------------------------------------
// Kernel 2: pred conv via MFMA, B staged densely from xT. Atomic K-split x4.
// grid = 1024, XCD-swizzled.
// ---------------------------------------------------------------------------
__global__ __launch_bounds__(256) void k_pred3(const ushort* __restrict__ xT,
                                               const ushort* __restrict__ w1F,
                                               float* __restrict__ P) {
    int bid = blockIdx.x;
    int L = (bid & 7) * 128 + (bid >> 3);
    int g = L & 3;
    int h = (L >> 2) & 63;
    int b = L >> 8;
    int tid = threadIdx.x;
    int spx  = tid & 63;
    int sgrp = tid >> 6;
    int lane = tid & 63;
    int wv   = tid >> 6;
    int l16  = lane & 15;
    int lq   = lane >> 4;

    __shared__ ushort b_lds[2][4][4][16][8];

    const ushort* xTb = xT + (size_t)b * HWSZ * 256;
    const bf16x8* w1v = (const bf16x8*)w1F;

    f32x4 acc[2];
    acc[0] = (f32x4){0.f, 0.f, 0.f, 0.f};
    acc[1] = (f32x4){0.f, 0.f, 0.f, 0.f};

    auto stage = [&](int t, int buf) {
        int cg = 2 * g + (t >= 9);
        int k = t - (t >= 9 ? 9 : 0);
        int y   = h + k / 3 - 1;
        int pxs = spx + k % 3 - 1;
        bool ok = (y >= 0 && y < HH && pxs >= 0 && pxs < WW);
        uint4 v = make_uint4(0u, 0u, 0u, 0u);
        if (ok) v = *(const uint4*)(xTb + (size_t)(y * WW + pxs) * 256 + cg * 32 + sgrp * 8);
        *(uint4*)&b_lds[buf][sgrp][spx >> 4][spx & 15][0] = v;
    };

    stage(0, 0);
    __syncthreads();

    for (int t = 0; t < 18; ++t) {
        int cur = t & 1;
        int cg = 2 * g + (t >= 9);
        int k  = t - (t >= 9 ? 9 : 0);
        int row = k * 32 + cg * 4 + lq;
        bf16x8 a0 = w1v[(size_t)row * 32 + 0 * 16 + l16];
        bf16x8 a1 = w1v[(size_t)row * 32 + 1 * 16 + l16];
        if (t < 17) stage(t + 1, cur ^ 1);
        bf16x8 bfrag = *(const bf16x8*)&b_lds[cur][lq][wv][l16][0];
        acc[0] = __builtin_amdgcn_mfma_f32_16x16x32_bf16(a0, bfrag, acc[0], 0, 0, 0);
        acc[1] = __builtin_amdgcn_mfma_f32_16x16x32_bf16(a1, bfrag, acc[1], 0, 0, 0);
        __syncthreads();
    }

#pragma unroll
    for (int mf = 0; mf < 2; ++mf) {
#pragma unroll
        for (int r = 0; r < 4; ++r) {
            int o = mf * 16 + lq * 4 + r;
            if (o < 27) {
                atomicAdd(&P[((size_t)b * 27 + o) * HWSZ + h * WW + wv * 16 + l16],
                          acc[mf][r]);
            }
        }
    }
}

// ---------------------------------------------------------------------------
// Kernel 3: deformable sampling + bf16 MFMA GEMM, deep-pipelined, STATIC regs.
// Tile 256o x 64px, 512 thr, cs-split x2, grid 512, XCD-swizzled.
// Explicit even/odd pair loop: named slots gbA/gbB (gathers, 2 chunks ahead),
// aA/aB (A-frags, 1 ahead), P reads 1 body ahead. No runtime-indexed arrays
// (rule #20 — R8's scratch-spill regression).
// ---------------------------------------------------------------------------
__global__ __launch_bounds__(512, 4) void k_deform8(const ushort* __restrict__ xT,
                                                    const float* __restrict__ P,
                                                    const float* __restrict__ b_off,
                                                    const ushort* __restrict__ w2F,
                                                    float* __restrict__ out) {
    int bid = blockIdx.x;
    int L = (bid & 7) * 64 + (bid >> 3);
    int cs = L & 1;
    int h  = (L >> 1) & 63;
    int b  = L >> 7;
    int tid = threadIdx.x;
    int lane = tid & 63;
    int wv   = tid >> 6;          // 0..7 -> o block = wv*32
    int l16  = lane & 15;
    int lq   = lane >> 4;
    int px   = tid >> 3;          // 0..63
    int cl   = tid & 7;           // 8-channel slot

    __shared__ ushort b_lds[2][8][4][16][8];   // [buf][kg][nt][p^kg][j] 16KB

    const char* xTc = (const char*)xT + (size_t)b * HWSZ * 512 + cs * 256 + cl * 16;
    const bf16x8* w2b = (const bf16x8*)w2F + (size_t)(cs * 16) * 256 + wv * 32 + l16;

    uint4* wdst0 = (uint4*)&b_lds[0][cl][px >> 4][(px & 15) ^ cl][0];
    uint4* wdst1 = (uint4*)&b_lds[1][cl][px >> 4][(px & 15) ^ cl][0];

    f32x4 acc[2][4];
#pragma unroll
    for (int mf = 0; mf < 2; ++mf)
#pragma unroll
        for (int nt = 0; nt < 4; ++nt) acc[mf][nt] = (f32x4){0.f, 0.f, 0.f, 0.f};

    const float* Pb = P + (size_t)b * 27 * HWSZ + h * WW + px;

    float pOy, pOx, pMr, bOy, bOx, bMr;
    float wgt[4];
    const char* aptr[4];

    auto loadP = [&](int k) {
        pOy = Pb[(size_t)(2 * k) * HWSZ];
        pOx = Pb[(size_t)(2 * k + 1) * HWSZ];
        pMr = Pb[(size_t)(18 + k) * HWSZ];
        bOy = b_off[2 * k];
        bOx = b_off[2 * k + 1];
        bMr = b_off[18 + k];
    };
    auto calcDesc = [&](int k) {
        float offy = pOy + bOy;
        float offx = pOx + bOx;
        float m = 1.0f / (1.0f + expf(-(pMr + bMr)));
        float sy = offy + (float)(h + k / 3 - 1);
        float sx = offx + (float)(px + k % 3 - 1);
        float y0f = floorf(sy), x0f = floorf(sx);
        float ty = sy - y0f, tx = sx - x0f;
        int y0 = (int)y0f, x0 = (int)x0f;
#pragma unroll
        for (int dy = 0; dy < 2; ++dy) {
#pragma unroll
            for (int dx = 0; dx < 2; ++dx) {
                int yi = y0 + dy, xi = x0 + dx;
                bool ok = (yi >= 0 && yi < HH && xi >= 0 && xi < WW);
                float wg = (dy ? ty : 1.0f - ty) * (dx ? tx : 1.0f - tx) * m;
                wgt[dy * 2 + dx]  = ok ? wg : 0.0f;
                aptr[dy * 2 + dx] = xTc + (size_t)(ok ? (yi * WW + xi) : 0) * 512;
            }
        }
    };

    // named pipeline slots (static indexing only)
    uint4 gbA[4], gbB[4];
    float wgtA[4], wgtB[4];
    bf16x8 aA[2][2], aB[2][2];

    auto issueGatherTo = [&](uint4 (&gb)[4], float (&wg)[4], int off) {
#pragma unroll
        for (int c = 0; c < 4; ++c) gb[c] = *(const uint4*)(aptr[c] + off);
#pragma unroll
        for (int c = 0; c < 4; ++c) wg[c] = wgt[c];
    };
    auto combineFrom = [&](const uint4 (&g)[4], const float (&w)[4]) -> uint4 {
        uint4 r;
        {
            float lo = w[0]*blo(g[0].x) + w[1]*blo(g[1].x) + w[2]*blo(g[2].x) + w[3]*blo(g[3].x);
            float hi = w[0]*bhi(g[0].x) + w[1]*bhi(g[1].x) + w[2]*bhi(g[2].x) + w[3]*bhi(g[3].x);
            r.x = bpack(lo, hi);
        }
        {
            float lo = w[0]*blo(g[0].y) + w[1]*blo(g[1].y) + w[2]*blo(g[2].y) + w[3]*blo(g[3].y);
            float hi = w[0]*bhi(g[0].y) + w[1]*bhi(g[1].y) + w[2]*bhi(g[2].y) + w[3]*bhi(g[3].y);
            r.y = bpack(lo, hi);
        }
        {
            float lo = w[0]*blo(g[0].z) + w[1]*blo(g[1].z) + w[2]*blo(g[2].z) + w[3]*blo(g[3].z);
            float hi = w[0]*bhi(g[0].z) + w[1]*bhi(g[1].z) + w[2]*bhi(g[2].z) + w[3]*bhi(g[3].z);
            r.z = bpack(lo, hi);
        }
        {
            float lo = w[0]*blo(g[0].w) + w[1]*blo(g[1].w) + w[2]*blo(g[2].w) + w[3]*blo(g[3].w);
            float hi = w[0]*bhi(g[0].w) + w[1]*bhi(g[1].w) + w[2]*bhi(g[2].w) + w[3]*bhi(g[3].w);
            r.w = bpack(lo, hi);
        }
        return r;
    };
    auto loadATo = [&](bf16x8 (&a)[2][2], int t) {
        size_t base = ((size_t)((t >> 1) * 32 + (t & 1) * 8) + lq) * 256;
#pragma unroll
        for (int g = 0; g < 2; ++g)
#pragma unroll
            for (int mf = 0; mf < 2; ++mf)
                a[mf][g] = w2b[base + (size_t)g * 1024 + mf * 16];
    };

#define MFMA_BODY(BUF, AREG)                                                        \
    do {                                                                            \
        bf16x8 bfr[2][4];                                                           \
        _Pragma("unroll")                                                           \
        for (int g = 0; g < 2; ++g) {                                               \
            int kg = g * 4 + lq;                                                    \
            _Pragma("unroll")                                                       \
            for (int nt = 0; nt < 4; ++nt)                                          \
                bfr[g][nt] = *(const bf16x8*)&b_lds[BUF][kg][nt][l16 ^ kg][0];      \
        }                                                                           \
        _Pragma("unroll")                                                           \
        for (int g = 0; g < 2; ++g)                                                 \
            _Pragma("unroll")                                                       \
            for (int mf = 0; mf < 2; ++mf)                                          \
                _Pragma("unroll")                                                   \
                for (int nt = 0; nt < 4; ++nt)                                      \
                    acc[mf][nt] = __builtin_amdgcn_mfma_f32_16x16x32_bf16(          \
                        AREG[mf][g], bfr[g][nt], acc[mf][nt], 0, 0, 0);             \
    } while (0)

    // --- prologue: chunks 0 (->gbA->buf0) and 1 (->gbB), A chunk 0 ---
    loadP(0);
    calcDesc(0);
    issueGatherTo(gbA, wgtA, 0);
    issueGatherTo(gbB, wgtB, 128);
    loadP(1);
    loadATo(aA, 0);
    *wdst0 = combineFrom(gbA, wgtA);
    __syncthreads();

    for (int tp = 0; tp < 9; ++tp) {
        // ---- even body: t = 2tp. reads buf0 / aA; combines gbB -> buf1 ----
        if (tp < 8) {
            calcDesc(tp + 1);                 // P loaded at previous odd body
            issueGatherTo(gbA, wgtA, 0);      // chunk 2tp+2 (k=tp+1, lo half)
        }
        loadATo(aB, 2 * tp + 1);
        MFMA_BODY(0, aA);
        *wdst1 = combineFrom(gbB, wgtB);      // chunk 2tp+1 -> buf1
        __syncthreads();

        // ---- odd body: t = 2tp+1. reads buf1 / aB; combines gbA -> buf0 ----
        if (tp < 8) {
            issueGatherTo(gbB, wgtB, 128);    // chunk 2tp+3 (k=tp+1, hi half)
            if (tp < 7) loadP(tp + 2);
            loadATo(aA, 2 * tp + 2);
        }
        MFMA_BODY(1, aB);
        if (tp < 8) {
            *wdst0 = combineFrom(gbA, wgtA);  // chunk 2tp+2 -> buf0
        }
        __syncthreads();
    }
#undef MFMA_BODY

    // epilogue: atomic accumulate (out prefilled with bias)
#pragma unroll
    for (int mf = 0; mf < 2; ++mf) {
#pragma unroll
        for (int nt = 0; nt < 4; ++nt) {
#pragma unroll
            for (int r = 0; r < 4; ++r) {
                int o = wv * 32 + mf * 16 + lq * 4 + r;
                atomicAdd(&out[((size_t)b * OCH + o) * HWSZ + h * WW + nt * 16 + l16],
                          acc[mf][nt][r]);
            }
        }
    }
}

// ---------------------------------------------------------------------------
extern "C" void kernel_launch(void* const* d_in, const int* in_sizes, int n_in,
                              void* d_out, int out_size, void* d_ws, size_t ws_size,
                              hipStream_t stream) {
    const float* x     = (const float*)d_in[0];
    const float* w_off = (const float*)d_in[1];
    const float* b_off = (const float*)d_in[2];
    const float* w_def = (const float*)d_in[3];
    const float* b_def = (const float*)d_in[4];
    float* out = (float*)d_out;

    float*  P   = (float*)d_ws;                            // 442368 f32
    ushort* w1F = (ushort*)(P + (size_t)BB * 27 * HWSZ);   // 73728 bf16
    ushort* w2F = w1F + 73728;                             // 589824 bf16
    ushort* xT  = w2F + 589824;                            // 4.19M bf16

    hipLaunchKernelGGL(k_prep, dim3(7120), dim3(256), 0, stream,
                       w_off, w_def, b_def, w1F, w2F, P, out);
    hipLaunchKernelGGL(k_xT, dim3(BB * HH), dim3(256), 0, stream, x, xT);
    hipLaunchKernelGGL(k_pred3, dim3(1024), dim3(256), 0, stream, xT, w1F, P);
    hipLaunchKernelGGL(k_deform8, dim3(512), dim3(512), 0, stream, xT, P, b_off, w2F, out);
}